// Round 1
// baseline (1144.023 us; speedup 1.0000x reference)
//
#include <hip/hip_runtime.h>
#include <hip/hip_bf16.h>

#define BB 8192
#define TT 8
#define DEe 512
#define DRr 1024
#define HH 1024
#define KTOT 2560   // 512 + 1024 + 1024

typedef __attribute__((ext_vector_type(8))) __bf16 bf16x8;
typedef __attribute__((ext_vector_type(4))) __bf16 bf16x4;
typedef __attribute__((ext_vector_type(4))) float f32x4;

__device__ __forceinline__ void gld_lds16(const __bf16* g, __bf16* l) {
    __builtin_amdgcn_global_load_lds(
        (const __attribute__((address_space(1))) void*)g,
        (__attribute__((address_space(3))) void*)l, 16, 0, 0);
}

// Pack ent[:,t,:] and rel[:,t,:] (f32) into bf16 rows of bufA [8192 x 2560].
// grid (3, 8192), block 128. sec 0: ent (512 cols), sec 1..2: rel (1024 cols).
__global__ void pack_a(const float* __restrict__ ent, const float* __restrict__ rel,
                       __bf16* __restrict__ buf, int t) {
    const int b = blockIdx.y;
    const int sec = blockIdx.x;
    const int i = threadIdx.x;
    float4 v; size_t dst;
    if (sec == 0) {
        v = *(const float4*)(ent + ((size_t)b * TT + t) * DEe + i * 4);
        dst = (size_t)b * KTOT + i * 4;
    } else {
        int d = (sec - 1) * 512 + i * 4;
        v = *(const float4*)(rel + ((size_t)b * TT + t) * DRr + d);
        dst = (size_t)b * KTOT + DEe + d;
    }
    bf16x4 o = {(__bf16)v.x, (__bf16)v.y, (__bf16)v.z, (__bf16)v.w};
    *(bf16x4*)(buf + dst) = o;
}

// Pack [We | Wr | Wh] rows into Bw [1024 x 2560] bf16. grid (5,1024), block 128.
__global__ void pack_b(const float* __restrict__ We, const float* __restrict__ Wr,
                       const float* __restrict__ Wh, __bf16* __restrict__ Bw) {
    const int n = blockIdx.y;
    const int sec = blockIdx.x;
    const int i = threadIdx.x;
    float4 v; size_t dst;
    if (sec == 0) {
        v = *(const float4*)(We + (size_t)n * DEe + i * 4);
        dst = (size_t)n * KTOT + i * 4;
    } else if (sec <= 2) {
        int d = (sec - 1) * 512 + i * 4;
        v = *(const float4*)(Wr + (size_t)n * DRr + d);
        dst = (size_t)n * KTOT + DEe + d;
    } else {
        int d = (sec - 3) * 512 + i * 4;
        v = *(const float4*)(Wh + (size_t)n * HH + d);
        dst = (size_t)n * KTOT + 1536 + d;
    }
    bf16x4 o = {(__bf16)v.x, (__bf16)v.y, (__bf16)v.z, (__bf16)v.w};
    *(bf16x4*)(Bw + dst) = o;
}

// One RNN step: C[M=8192, N=1024] = relu(A[8192,K] @ Bw[1024,K]^T + bias)
// m97 structure: 128x128 tile, BK=32, 4 waves (2x2 of 64x64), 16x16x32 bf16 MFMA,
// global_load_lds width 16. Epilogue: +bias, relu, f32 -> out[:,t,:],
// bf16 -> Anext h-section, t==7 also transposed need[h][b].
__global__ __launch_bounds__(256) void gemm_step(
    const __bf16* __restrict__ A, const __bf16* __restrict__ Bw,
    const float* __restrict__ be, const float* __restrict__ br,
    const float* __restrict__ bh,
    float* __restrict__ out, __bf16* __restrict__ Anext,
    float* __restrict__ need, int K, int t) {
    __shared__ __bf16 sA[128 * 32];
    __shared__ __bf16 sB[128 * 32];
    __shared__ float sBias[128];

    const int tid  = threadIdx.x;
    const int lane = tid & 63;
    const int w    = tid >> 6;
    const int tileM = blockIdx.y * 128;
    const int tileN = blockIdx.x * 128;

    if (tid < 128) {
        int n = tileN + tid;
        sBias[tid] = be[n] + br[n] + bh[n];
    }

    // staging geometry: instr j of wave w fills LDS bytes (w*2+j)*1024 + lane*16
    const int r0 = (w * 2 + 0) * 16 + (lane >> 2);
    const int r1 = (w * 2 + 1) * 16 + (lane >> 2);
    const int cc = (lane & 3) * 8;
    const __bf16* gA0 = A + (size_t)(tileM + r0) * KTOT + cc;
    const __bf16* gA1 = A + (size_t)(tileM + r1) * KTOT + cc;
    const __bf16* gB0 = Bw + (size_t)(tileN + r0) * KTOT + cc;
    const __bf16* gB1 = Bw + (size_t)(tileN + r1) * KTOT + cc;
    __bf16* lA0 = sA + (w * 2 + 0) * 512;
    __bf16* lA1 = sA + (w * 2 + 1) * 512;
    __bf16* lB0 = sB + (w * 2 + 0) * 512;
    __bf16* lB1 = sB + (w * 2 + 1) * 512;

    const int wm = (w >> 1) * 64, wn = (w & 1) * 64;
    const int fm = lane & 15, fq = lane >> 4;

    f32x4 acc[4][4];
#pragma unroll
    for (int i = 0; i < 4; i++)
#pragma unroll
        for (int j = 0; j < 4; j++) acc[i][j] = {0.f, 0.f, 0.f, 0.f};

    for (int k0 = 0; k0 < K; k0 += 32) {
        gld_lds16(gA0 + k0, lA0);
        gld_lds16(gA1 + k0, lA1);
        gld_lds16(gB0 + k0, lB0);
        gld_lds16(gB1 + k0, lB1);
        __syncthreads();
        bf16x8 af[4], bf[4];
#pragma unroll
        for (int mf = 0; mf < 4; mf++)
            af[mf] = *(const bf16x8*)&sA[(wm + mf * 16 + fm) * 32 + fq * 8];
#pragma unroll
        for (int nf = 0; nf < 4; nf++)
            bf[nf] = *(const bf16x8*)&sB[(wn + nf * 16 + fm) * 32 + fq * 8];
#pragma unroll
        for (int mf = 0; mf < 4; mf++)
#pragma unroll
            for (int nf = 0; nf < 4; nf++)
                acc[mf][nf] = __builtin_amdgcn_mfma_f32_16x16x32_bf16(
                    af[mf], bf[nf], acc[mf][nf], 0, 0, 0);
        __syncthreads();
    }

    // epilogue: C/D layout col = lane&15, row = (lane>>4)*4 + reg
#pragma unroll
    for (int mf = 0; mf < 4; mf++) {
#pragma unroll
        for (int nf = 0; nf < 4; nf++) {
            f32x4 v = acc[mf][nf];
            const int nl = wn + nf * 16 + fm;   // n within tile
            const int n  = tileN + nl;
            const int m0 = tileM + wm + mf * 16 + fq * 4;
            const float bias = sBias[nl];
            float hv[4];
#pragma unroll
            for (int r = 0; r < 4; r++) {
                float x = v[r] + bias;
                hv[r] = x > 0.f ? x : 0.f;
                out[(size_t)(m0 + r) * (TT * HH) + (size_t)t * HH + n] = hv[r];
                if (Anext)
                    Anext[(size_t)(m0 + r) * KTOT + 1536 + n] = (__bf16)hv[r];
            }
            if (need) {
                f32x4 nv = {hv[0], hv[1], hv[2], hv[3]};
                *(f32x4*)&need[(size_t)n * BB + m0] = nv;
            }
        }
    }
}

extern "C" void kernel_launch(void* const* d_in, const int* in_sizes, int n_in,
                              void* d_out, int out_size, void* d_ws, size_t ws_size,
                              hipStream_t stream) {
    const float* ent = (const float*)d_in[0];
    const float* rel = (const float*)d_in[1];
    const float* We  = (const float*)d_in[2];
    const float* be  = (const float*)d_in[3];
    const float* Wr  = (const float*)d_in[4];
    const float* br  = (const float*)d_in[5];
    const float* Wh  = (const float*)d_in[6];
    const float* bh  = (const float*)d_in[7];

    float* out  = (float*)d_out;
    float* need = out + (size_t)BB * TT * HH;   // [H, B] region

    char* ws = (char*)d_ws;
    __bf16* buf0 = (__bf16*)ws;                                  // 8192*2560*2 B
    __bf16* buf1 = (__bf16*)(ws + (size_t)BB * KTOT * 2);
    __bf16* Bw   = (__bf16*)(ws + (size_t)2 * BB * KTOT * 2);    // 1024*2560*2 B
    __bf16* bufs[2] = {buf0, buf1};

    pack_b<<<dim3(5, 1024), 128, 0, stream>>>(We, Wr, Wh, Bw);
    for (int t = 0; t < TT; t++) {
        pack_a<<<dim3(3, BB), 128, 0, stream>>>(ent, rel, bufs[t & 1], t);
        gemm_step<<<dim3(8, 64), 256, 0, stream>>>(
            bufs[t & 1], Bw, be, br, bh, out,
            (t < 7) ? bufs[(t + 1) & 1] : nullptr,
            (t == 7) ? need : nullptr,
            (t == 0) ? 1536 : KTOT, t);
    }
}